// Round 2
// baseline (3161.799 us; speedup 1.0000x reference)
//
#include <hip/hip_runtime.h>

#define B_   32
#define N_   64
#define IN_  2048
#define D_   32
#define K_   16
#define ITILE 8
#define NBLK (IN_/ITILE)        /* 256 blocks */
#define CELLS ((size_t)B_*N_*D_) /* 65536 */

// softmax_e(v * INV_LOG2) => exp2((v-max) * (1/ln2)^2)
#define SM_SCALE 2.0813689810056077f

// -----------------------------------------------------------------------------
// route_kernel: one full pass over W. Recomputes u_hat[b,n,i,d] on the fly,
// computes routing coefficients c (softmax over n of u_hat . out_sum), and
// accumulates s_partial[b,n,d] = sum_{i in block} c * u_hat into a per-block
// partial buffer.  FIRST=true is iteration 0 (b-logits = 0 -> c = 1/64).
// -----------------------------------------------------------------------------
template<bool FIRST>
__global__ __launch_bounds__(1024)
void route_kernel(const float* __restrict__ x, const float* __restrict__ W,
                  const float* __restrict__ os, float* __restrict__ part, int P)
{
    __shared__ float x_s[B_][K_];          // 2 KB: x[b][k] for current i
    __shared__ float logit_s[2][8][N_];    // 4 KB: double-buffered logits/c

    const int tid  = threadIdx.x;
    const int w    = tid >> 6;      // wave 0..15
    const int l    = tid & 63;      // lane
    const int d    = l & 31;        // output dim this thread owns
    const int hi   = l >> 5;        // half-wave
    const int slot = w * 2 + hi;    // 0..31
    const int nA   = slot;          // capsule rows this thread owns
    const int nB   = slot + 32;

    float s_acc[2][B_];             // 64 VGPRs: accumulated c*u_hat
    #pragma unroll
    for (int p = 0; p < 2; ++p)
        #pragma unroll
        for (int b = 0; b < B_; ++b) s_acc[p][b] = 0.f;

    const int i0 = blockIdx.x * ITILE;

    for (int ii = 0; ii < ITILE; ++ii) {
        const int i = i0 + ii;
        __syncthreads();                       // protect x_s from prev readers
        if (tid < B_ * K_) {                   // 512 threads load x slice
            const int b = tid >> 4, k = tid & 15;
            x_s[b][k] = x[(size_t)b * (IN_ * K_) + (size_t)i * K_ + k];
        }
        __syncthreads();

        // this thread's two W rows: W[n, i, d, 0..15]  (16 floats each)
        const float4* WA = (const float4*)(W + (((size_t)nA * IN_ + i) * D_ + d) * K_);
        const float4* WB = (const float4*)(W + (((size_t)nB * IN_ + i) * D_ + d) * K_);
        const float4 wa0 = WA[0], wa1 = WA[1], wa2 = WA[2], wa3 = WA[3];
        const float4 wb0 = WB[0], wb1 = WB[1], wb2 = WB[2], wb3 = WB[3];

        #pragma unroll
        for (int c = 0; c < 4; ++c) {          // b-chunks of 8
            float uhA[8], uhB[8];
            #pragma unroll
            for (int j = 0; j < 8; ++j) {
                const int b = c * 8 + j;
                const float4 x0 = *(const float4*)&x_s[b][0];
                const float4 x1 = *(const float4*)&x_s[b][4];
                const float4 x2 = *(const float4*)&x_s[b][8];
                const float4 x3 = *(const float4*)&x_s[b][12];
                uhA[j] = wa0.x*x0.x + wa0.y*x0.y + wa0.z*x0.z + wa0.w*x0.w
                       + wa1.x*x1.x + wa1.y*x1.y + wa1.z*x1.z + wa1.w*x1.w
                       + wa2.x*x2.x + wa2.y*x2.y + wa2.z*x2.z + wa2.w*x2.w
                       + wa3.x*x3.x + wa3.y*x3.y + wa3.z*x3.z + wa3.w*x3.w;
                uhB[j] = wb0.x*x0.x + wb0.y*x0.y + wb0.z*x0.z + wb0.w*x0.w
                       + wb1.x*x1.x + wb1.y*x1.y + wb1.z*x1.z + wb1.w*x1.w
                       + wb2.x*x2.x + wb2.y*x2.y + wb2.z*x2.z + wb2.w*x2.w
                       + wb3.x*x3.x + wb3.y*x3.y + wb3.z*x3.z + wb3.w*x3.w;
            }

            if (FIRST) {
                // b-logits are zero -> c = 1/64 uniform; fold 1/64 at store.
                #pragma unroll
                for (int j = 0; j < 8; ++j) {
                    s_acc[0][c*8+j] += uhA[j];
                    s_acc[1][c*8+j] += uhB[j];
                }
            } else {
                // logits[b][n] = sum_d u_hat * out_sum   (reduce over 32 lanes)
                #pragma unroll
                for (int j = 0; j < 8; ++j) {
                    const int b = c * 8 + j;
                    float tA = uhA[j] * os[((size_t)b * N_ + nA) * D_ + d];
                    float tB = uhB[j] * os[((size_t)b * N_ + nB) * D_ + d];
                    #pragma unroll
                    for (int m = 1; m < 32; m <<= 1) {
                        tA += __shfl_xor(tA, m, 64);
                        tB += __shfl_xor(tB, m, 64);
                    }
                    if (d == 0) {
                        logit_s[c & 1][j][nA] = tA;
                        logit_s[c & 1][j][nB] = tB;
                    }
                }
                __syncthreads();
                // softmax over n: softmax_e(v*INV_LOG2) == 2^((v-max)*SM_SCALE)
                if (w < 8) {
                    const float v = logit_s[c & 1][w][l];
                    float mx = v;
                    #pragma unroll
                    for (int m = 1; m < 64; m <<= 1) mx = fmaxf(mx, __shfl_xor(mx, m, 64));
                    const float e = exp2f((v - mx) * SM_SCALE);
                    float sum = e;
                    #pragma unroll
                    for (int m = 1; m < 64; m <<= 1) sum += __shfl_xor(sum, m, 64);
                    logit_s[c & 1][w][l] = e / sum;
                }
                __syncthreads();
                #pragma unroll
                for (int j = 0; j < 8; ++j) {
                    s_acc[0][c*8+j] += logit_s[c & 1][j][nA] * uhA[j];
                    s_acc[1][c*8+j] += logit_s[c & 1][j][nB] * uhB[j];
                }
                // no third barrier: logit_s is double-buffered on (c&1)
            }
        }
    }

    // write per-block partial s
    const float scale = FIRST ? (1.0f / 64.0f) : 1.0f;
    float* myp = part + (size_t)(blockIdx.x % P) * CELLS;
    if (P == NBLK) {
        #pragma unroll
        for (int b = 0; b < B_; ++b) {
            myp[((size_t)b * N_ + nA) * D_ + d] = s_acc[0][b] * scale;
            myp[((size_t)b * N_ + nB) * D_ + d] = s_acc[1][b] * scale;
        }
    } else {
        for (int b = 0; b < B_; ++b) {
            atomicAdd(&myp[((size_t)b * N_ + nA) * D_ + d], s_acc[0][b] * scale);
            atomicAdd(&myp[((size_t)b * N_ + nB) * D_ + d], s_acc[1][b] * scale);
        }
    }
}

// -----------------------------------------------------------------------------
// finish_kernel: s = sum_p partial[p]; out = squash(s);
// FINAL=false: out_sum += out (for next routing pass); FINAL=true: write d_out.
// -----------------------------------------------------------------------------
template<bool FINAL>
__global__ __launch_bounds__(256)
void finish_kernel(const float* __restrict__ part, int P,
                   float* __restrict__ os, float* __restrict__ out)
{
    const int gid = blockIdx.x * 256 + threadIdx.x;   // 0..65535
    float v = 0.f;
    for (int p = 0; p < P; ++p) v += part[(size_t)p * CELLS + gid];
    float sq = v * v;
    #pragma unroll
    for (int m = 1; m < 32; m <<= 1) sq += __shfl_xor(sq, m, 64);  // sum over d
    const float scale = sqrtf(sq) / (1.0f + sq);
    const float o = v * scale;
    if (FINAL) out[gid] = o;
    else       os[gid] += o;
}

extern "C" void kernel_launch(void* const* d_in, const int* in_sizes, int n_in,
                              void* d_out, int out_size, void* d_ws, size_t ws_size,
                              hipStream_t stream)
{
    const float* x = (const float*)d_in[0];
    const float* W = (const float*)d_in[1];
    float* out = (float*)d_out;

    // ws: [P][CELLS] partials + [CELLS] out_sum
    int P = NBLK;
    if (ws_size < (size_t)(NBLK + 1) * CELLS * 4) {
        long long avail = (long long)(ws_size / 4) - (long long)CELLS;
        long long p = avail > 0 ? avail / (long long)CELLS : 1;
        P = (int)p; if (P < 1) P = 1; if (P > NBLK) P = NBLK;
    }
    float* part = (float*)d_ws;
    float* os   = part + (size_t)P * CELLS;

    hipMemsetAsync(os, 0, CELLS * 4, stream);
    const bool atomics = (P < NBLK);

    for (int it = 0; it < 3; ++it) {
        if (atomics) hipMemsetAsync(part, 0, (size_t)P * CELLS * 4, stream);
        if (it == 0) route_kernel<true ><<<NBLK, 1024, 0, stream>>>(x, W, os, part, P);
        else         route_kernel<false><<<NBLK, 1024, 0, stream>>>(x, W, os, part, P);
        if (it < 2)  finish_kernel<false><<<256, 256, 0, stream>>>(part, P, os, nullptr);
        else         finish_kernel<true ><<<256, 256, 0, stream>>>(part, P, nullptr, out);
    }
}

// Round 3
// 2649.206 us; speedup vs baseline: 1.1935x; 1.1935x over previous
//
#include <hip/hip_runtime.h>

#define B_    32
#define N_    64
#define IN_   2048
#define D_    32
#define K_    16
#define ITILE 16
#define NTILE (IN_/ITILE)          /* 128 i-tiles */
#define NBLK  (NTILE*2)            /* 256 blocks = tiles x 2 batch-halves */
#define BH    16                   /* batches per block */
#define PCELLS ((size_t)BH*N_*D_)  /* 32768 */
#define CELLS  ((size_t)B_*N_*D_)  /* 65536 */

// softmax_e(v * INV_LOG2) == 2^((v-max) * (1/ln2)^2)
#define SM_SCALE 2.0813689810056077f

// -----------------------------------------------------------------------------
// route_kernel: one pass over W. Block = (i-tile, batch-half). Recomputes
// u_hat on the fly, fuses logits+softmax+weighted sum. Pairs (2t,2t+1) read
// the same W i-tile back-to-back -> L3 dedups the second fetch.
// b-split keeps s_acc at 32 VGPRs so nothing spills.
// -----------------------------------------------------------------------------
template<bool FIRST>
__global__ __launch_bounds__(1024, 4)
void route_kernel(const float* __restrict__ x, const float* __restrict__ W,
                  const float* __restrict__ os, float* __restrict__ part, int P)
{
    __shared__ float x_s[BH][K_];          // 1 KB
    __shared__ float logit_s[2][8][N_];    // 4 KB double-buffered

    const int tid  = threadIdx.x;
    const int w    = tid >> 6;      // wave 0..15
    const int l    = tid & 63;
    const int d    = l & 31;        // output dim
    const int hi   = l >> 5;
    const int slot = w * 2 + hi;    // 0..31
    const int nA   = slot;
    const int nB   = slot + 32;

    const int tile = blockIdx.x >> 1;
    const int bh   = blockIdx.x & 1;
    const int b0   = bh * BH;
    const int i0   = tile * ITILE;

    float s_acc[2][BH];             // 32 VGPRs
    #pragma unroll
    for (int p = 0; p < 2; ++p)
        #pragma unroll
        for (int b = 0; b < BH; ++b) s_acc[p][b] = 0.f;

    const float* wpA = W + (((size_t)nA * IN_ + i0) * D_ + d) * K_;
    const float* wpB = W + (((size_t)nB * IN_ + i0) * D_ + d) * K_;

    for (int ii = 0; ii < ITILE; ++ii) {
        __syncthreads();                          // x_s safe to overwrite
        if (tid < BH * (K_ / 4)) {                // 64 threads, float4 each
            const int b = tid >> 2, k4 = tid & 3;
            ((float4*)x_s[b])[k4] =
                ((const float4*)(x + (size_t)(b0 + b) * (IN_ * K_)
                                   + (size_t)(i0 + ii) * K_))[k4];
        }
        __syncthreads();

        const float4 wa0 = ((const float4*)wpA)[0], wa1 = ((const float4*)wpA)[1],
                     wa2 = ((const float4*)wpA)[2], wa3 = ((const float4*)wpA)[3];
        const float4 wb0 = ((const float4*)wpB)[0], wb1 = ((const float4*)wpB)[1],
                     wb2 = ((const float4*)wpB)[2], wb3 = ((const float4*)wpB)[3];
        wpA += (size_t)D_ * K_;
        wpB += (size_t)D_ * K_;

        auto dot2 = [&](int b, float& ua, float& ub) {
            const float4 x0 = ((const float4*)x_s[b])[0];
            const float4 x1 = ((const float4*)x_s[b])[1];
            const float4 x2 = ((const float4*)x_s[b])[2];
            const float4 x3 = ((const float4*)x_s[b])[3];
            ua = wa0.x*x0.x + wa0.y*x0.y + wa0.z*x0.z + wa0.w*x0.w
               + wa1.x*x1.x + wa1.y*x1.y + wa1.z*x1.z + wa1.w*x1.w
               + wa2.x*x2.x + wa2.y*x2.y + wa2.z*x2.z + wa2.w*x2.w
               + wa3.x*x3.x + wa3.y*x3.y + wa3.z*x3.z + wa3.w*x3.w;
            ub = wb0.x*x0.x + wb0.y*x0.y + wb0.z*x0.z + wb0.w*x0.w
               + wb1.x*x1.x + wb1.y*x1.y + wb1.z*x1.z + wb1.w*x1.w
               + wb2.x*x2.x + wb2.y*x2.y + wb2.z*x2.z + wb2.w*x2.w
               + wb3.x*x3.x + wb3.y*x3.y + wb3.z*x3.z + wb3.w*x3.w;
        };

        if (FIRST) {
            // c uniform (1/64, folded at store): accumulate dots directly
            #pragma unroll
            for (int jb = 0; jb < BH; ++jb) {
                float ua, ub;
                dot2(jb, ua, ub);
                s_acc[0][jb] += ua;
                s_acc[1][jb] += ub;
            }
        } else {
            #pragma unroll
            for (int ch = 0; ch < 2; ++ch) {       // 2 chunks of 8 batches
                float uhA[8], uhB[8];
                #pragma unroll
                for (int j = 0; j < 8; ++j) dot2(ch * 8 + j, uhA[j], uhB[j]);

                #pragma unroll
                for (int j = 0; j < 8; ++j) {      // logits: reduce over d
                    const int b = b0 + ch * 8 + j;
                    float tA = uhA[j] * os[((size_t)b * N_ + nA) * D_ + d];
                    float tB = uhB[j] * os[((size_t)b * N_ + nB) * D_ + d];
                    #pragma unroll
                    for (int m = 1; m < 32; m <<= 1) {
                        tA += __shfl_xor(tA, m, 64);
                        tB += __shfl_xor(tB, m, 64);
                    }
                    if (d == 0) {
                        logit_s[ch][j][nA] = tA;
                        logit_s[ch][j][nB] = tB;
                    }
                }
                __syncthreads();
                if (w < 8) {                       // softmax over n, wave=batch
                    const float v = logit_s[ch][w][l];
                    float mx = v;
                    #pragma unroll
                    for (int m = 1; m < 64; m <<= 1) mx = fmaxf(mx, __shfl_xor(mx, m, 64));
                    const float e = exp2f((v - mx) * SM_SCALE);
                    float sum = e;
                    #pragma unroll
                    for (int m = 1; m < 64; m <<= 1) sum += __shfl_xor(sum, m, 64);
                    logit_s[ch][w][l] = e / sum;
                }
                __syncthreads();
                #pragma unroll
                for (int j = 0; j < 8; ++j) {
                    s_acc[0][ch * 8 + j] += logit_s[ch][j][nA] * uhA[j];
                    s_acc[1][ch * 8 + j] += logit_s[ch][j][nB] * uhB[j];
                }
                // no extra barrier: logit_s double-buffered on ch parity;
                // next write to this parity is 2 barriers away
            }
        }
    }

    const float scale = FIRST ? (1.0f / 64.0f) : 1.0f;
    if (P == NBLK) {
        // compact layout: part[bid][jb][n][d]
        float* myp = part + (size_t)blockIdx.x * PCELLS;
        #pragma unroll
        for (int jb = 0; jb < BH; ++jb) {
            myp[((size_t)jb * N_ + nA) * D_ + d] = s_acc[0][jb] * scale;
            myp[((size_t)jb * N_ + nB) * D_ + d] = s_acc[1][jb] * scale;
        }
    } else {
        // fallback: atomics into [slot][global cells]
        float* myp = part + (size_t)(blockIdx.x % P) * CELLS;
        for (int jb = 0; jb < BH; ++jb) {
            const int b = b0 + jb;
            atomicAdd(&myp[((size_t)b * N_ + nA) * D_ + d], s_acc[0][jb] * scale);
            atomicAdd(&myp[((size_t)b * N_ + nB) * D_ + d], s_acc[1][jb] * scale);
        }
    }
}

// -----------------------------------------------------------------------------
// finish_kernel: s = sum of partials; out = squash(s);
// FINAL=false: os += out (next pass's logit operand); FINAL=true: write d_out.
// -----------------------------------------------------------------------------
template<bool FINAL>
__global__ __launch_bounds__(256)
void finish_kernel(const float* __restrict__ part, int P, int compact,
                   float* __restrict__ os, float* __restrict__ out)
{
    const int gid = blockIdx.x * 256 + threadIdx.x;   // 0..65535
    float v = 0.f;
    if (compact) {
        const int b   = gid >> 11;        // 0..31
        const int rem = gid & 2047;       // n*32+d
        const int bhh = b >> 4, jb = b & 15;
        const float* p0 = part + (size_t)bhh * PCELLS + (size_t)jb * (N_ * D_) + rem;
        for (int t = 0; t < NTILE; ++t) v += p0[(size_t)t * 2 * PCELLS];
    } else {
        for (int p = 0; p < P; ++p) v += part[(size_t)p * CELLS + gid];
    }
    float sq = v * v;
    #pragma unroll
    for (int m = 1; m < 32; m <<= 1) sq += __shfl_xor(sq, m, 64);  // sum over d
    const float scale = sqrtf(sq) / (1.0f + sq);
    const float o = v * scale;
    if (FINAL) out[gid] = o;
    else       os[gid] += o;
}

extern "C" void kernel_launch(void* const* d_in, const int* in_sizes, int n_in,
                              void* d_out, int out_size, void* d_ws, size_t ws_size,
                              hipStream_t stream)
{
    const float* x = (const float*)d_in[0];
    const float* W = (const float*)d_in[1];
    float* out = (float*)d_out;

    int P = NBLK;
    int compact = 1;
    float* part = (float*)d_ws;
    float* os;
    const size_t need = (size_t)NBLK * PCELLS * 4 + CELLS * 4;
    if (ws_size >= need) {
        os = part + (size_t)NBLK * PCELLS;
    } else {
        compact = 0;
        long long avail = (long long)(ws_size / 4) - (long long)CELLS;
        long long p = avail > 0 ? avail / (long long)CELLS : 1;
        P = (int)p; if (P < 1) P = 1; if (P > NBLK) P = NBLK;
        os = part + (size_t)P * CELLS;
    }

    hipMemsetAsync(os, 0, CELLS * 4, stream);

    for (int it = 0; it < 3; ++it) {
        if (!compact) hipMemsetAsync(part, 0, (size_t)P * CELLS * 4, stream);
        if (it == 0) route_kernel<true ><<<NBLK, 1024, 0, stream>>>(x, W, os, part, compact ? NBLK : P);
        else         route_kernel<false><<<NBLK, 1024, 0, stream>>>(x, W, os, part, compact ? NBLK : P);
        if (it < 2)  finish_kernel<false><<<CELLS / 256, 256, 0, stream>>>(part, P, compact, os, nullptr);
        else         finish_kernel<true ><<<CELLS / 256, 256, 0, stream>>>(part, P, compact, nullptr, out);
    }
}